// Round 2
// baseline (122.056 us; speedup 1.0000x reference)
//
#include <hip/hip_runtime.h>
#include <stdint.h>

// LocallyConnected1d: out[b,c,o] = (1/8) * sum_{i<64,k<8} x[b,i,4o+k] * w[c,i,o,k]
// B=128, CIN=64, COUT=64, OUT_DIM=256, K=8, S=4, L=1028. fp32 in/out.
//
// R5: FUSED single kernel, no workspace. The two-phase R4 (wprep -> wb -> gemm)
// paid: an extra launch + full dependency drain between kernels, a 33.5 MB wb
// HBM round-trip, and (suspected) the harness's 42 us workspace re-poison in
// the timed path. Profile showed each kernel < 41 us but e2e 117.6 us.
// Here each block transposes its own q's w slice (256 KB fp32) straight into
// the swizzled LDS B-tile. The 4 b-quarter blocks sharing q sit on the same
// XCD (swizzle kept), so w fp32 is read from HBM once and L2-hit 3 more times.
// Compute loop / A-staging / epilogue are byte-identical to the verified R4.

#define B_    128
#define CIN_  64
#define COUT_ 64
#define OD_   256
#define K_    8
#define L_    1028

#define ASTR 20   // A_lds row stride in bf16 elems (40 B: non-pow2 -> <=2-way banks)

typedef __attribute__((ext_vector_type(8))) short bf16x8;
typedef __attribute__((ext_vector_type(4))) short short4v;
typedef __attribute__((ext_vector_type(4))) float floatx4;

__device__ __forceinline__ unsigned short f32_to_bf16(float f) {
    union { float f; uint32_t u; } v; v.f = f;
    uint32_t u = v.u;
    u += 0x7FFFu + ((u >> 16) & 1u);   // round-to-nearest-even
    return (unsigned short)(u >> 16);
}

// ---------------- fused kernel: block = (q, b-quarter), grid 512 ----------------
__global__ __launch_bounds__(256, 2)
void lc1d_fused(const float* __restrict__ x,
                const float* __restrict__ w,
                float* __restrict__ out) {
    // Bl layout: [o_lo 2][c 64][gs 16][k 8] bf16, gs = i_loc ^ (c&7)  (32 KB)
    __shared__ __align__(16) unsigned short Bl[16384];
    __shared__ __align__(16) unsigned short Al[16 * 32 * ASTR];  // 20 KB

    const int tid = threadIdx.x;
    const int blk = blockIdx.x;
    // XCD swizzle: XCD k hosts q in [16k,16k+16) for all b-quarters
    const int q   = (blk & 7) * 16 + ((blk >> 3) & 15);
    const int bq  = blk >> 7;           // 0..3
    const int b0  = bq * 32;

    const int wave = tid >> 6;
    const int lane = tid & 63;
    const int quad = lane >> 4;
    const int l16  = lane & 15;
    const int o_lo = wave & 1;          // which o of the pair
    const int ms   = wave >> 1;         // m-stripe (16 b rows)

    // B-staging thread mapping: row u = it*256 + tid -> c = it*16 + (tid>>4), iL = tid&15
    const int iLs = tid & 15;
    const int cLo = tid >> 4;           // 0..15

    floatx4 acc[4];
    #pragma unroll
    for (int nt = 0; nt < 4; ++nt) acc[nt] = (floatx4){0.f, 0.f, 0.f, 0.f};

    for (int ch = 0; ch < 4; ++ch) {
        // ---- B staging: w fp32 -> Bl bf16, transpose + bank-XOR, in-block ----
        // per (c, i): 16 contiguous floats = [o_lo=0: k0..7 | o_lo=1: k0..7]
        #pragma unroll
        for (int it = 0; it < 4; ++it) {
            const int c = it * 16 + cLo;
            const float4* p = (const float4*)(w +
                ((size_t)(c * CIN_ + ch * 16 + iLs) * OD_ + q * 2) * K_);
            const float4 v0 = p[0];
            const float4 v1 = p[1];
            const float4 v2 = p[2];
            const float4 v3 = p[3];
            bf16x8 g0, g1;
            g0[0] = f32_to_bf16(v0.x); g0[1] = f32_to_bf16(v0.y);
            g0[2] = f32_to_bf16(v0.z); g0[3] = f32_to_bf16(v0.w);
            g0[4] = f32_to_bf16(v1.x); g0[5] = f32_to_bf16(v1.y);
            g0[6] = f32_to_bf16(v1.z); g0[7] = f32_to_bf16(v1.w);
            g1[0] = f32_to_bf16(v2.x); g1[1] = f32_to_bf16(v2.y);
            g1[2] = f32_to_bf16(v2.z); g1[3] = f32_to_bf16(v2.w);
            g1[4] = f32_to_bf16(v3.x); g1[5] = f32_to_bf16(v3.y);
            g1[6] = f32_to_bf16(v3.z); g1[7] = f32_to_bf16(v3.w);
            const int gs = iLs ^ (c & 7);
            *(bf16x8*)&Bl[(c * 16 + gs) << 3]        = g0;   // o_lo = 0
            *(bf16x8*)&Bl[((64 + c) * 16 + gs) << 3] = g1;   // o_lo = 1
        }

        // ---- x staging: rows (b,i) x 12 floats [8q, 8q+12) covering both o's ----
        #pragma unroll
        for (int it = 0; it < 8; ++it) {
            const int u   = it * 256 + tid;
            const int t   = u & 3;          // float4 within row; t==3 unused/masked
            const int row = u >> 2;         // 0..511
            const int iL  = row & 15;
            const int b   = row >> 4;       // 0..31
            if (t < 3) {
                const float4 v = *(const float4*)(x +
                    (size_t)((b0 + b) * CIN_ + ch * 16 + iL) * L_ + q * 8 + t * 4);
                ushort4 sv = make_ushort4(f32_to_bf16(v.x), f32_to_bf16(v.y),
                                          f32_to_bf16(v.z), f32_to_bf16(v.w));
                *(ushort4*)&Al[(iL * 32 + b) * ASTR + t * 4] = sv;
            }
        }
        __syncthreads();   // staging visible to all waves

        // ---- compute: 4 k-steps of 32 (i_loc = kt*4+quad, k=quad*8+j) ----
        #pragma unroll
        for (int kt = 0; kt < 4; ++kt) {
            const int i_l   = kt * 4 + quad;
            const int abase = (i_l * 32 + ms * 16 + l16) * ASTR + o_lo * 4;
            const short4v a_lo = *(const short4v*)&Al[abase];
            const short4v a_hi = *(const short4v*)&Al[abase + 4];
            bf16x8 af;
            af[0] = a_lo[0]; af[1] = a_lo[1]; af[2] = a_lo[2]; af[3] = a_lo[3];
            af[4] = a_hi[0]; af[5] = a_hi[1]; af[6] = a_hi[2]; af[7] = a_hi[3];
            #pragma unroll
            for (int nt = 0; nt < 4; ++nt) {
                const int c  = nt * 16 + l16;
                const int gs = i_l ^ (c & 7);
                const bf16x8 bf = *(const bf16x8*)&Bl[((o_lo * 64 + c) * 16 + gs) << 3];
                acc[nt] = __builtin_amdgcn_mfma_f32_16x16x32_bf16(af, bf, acc[nt], 0, 0, 0);
            }
        }
        __syncthreads();   // LDS reads done before next chunk overwrites
    }

    // ---- epilogue: D col=lane&15 (c), row=quad*4+reg (b); scale 1/sqrt(64) ----
    const int o_g = q * 2 + o_lo;
    #pragma unroll
    for (int nt = 0; nt < 4; ++nt) {
        const int c = nt * 16 + l16;
        #pragma unroll
        for (int r = 0; r < 4; ++r) {
            const int b = b0 + ms * 16 + quad * 4 + r;
            out[((size_t)b * COUT_ + c) * OD_ + o_g] = acc[nt][r] * 0.125f;
        }
    }
}

extern "C" void kernel_launch(void* const* d_in, const int* in_sizes, int n_in,
                              void* d_out, int out_size, void* d_ws, size_t ws_size,
                              hipStream_t stream) {
    const float* x = (const float*)d_in[0];   // (128, 64, 1028)
    const float* w = (const float*)d_in[1];   // (1, 64, 64, 256, 8)
    float* out = (float*)d_out;               // (128, 64, 256)
    (void)d_ws; (void)ws_size;                // workspace unused (R5: fused, no wb)

    hipLaunchKernelGGL(lc1d_fused, dim3(512), dim3(256), 0, stream, x, w, out);
}

// Round 3
// 121.553 us; speedup vs baseline: 1.0041x; 1.0041x over previous
//
#include <hip/hip_runtime.h>
#include <stdint.h>

// LocallyConnected1d: out[b,c,o] = (1/8) * sum_{i<64,k<8} x[b,i,4o+k] * w[c,i,o,k]
// B=128, CIN=64, COUT=64, OUT_DIM=256, K=8, S=4, L=1028. fp32 in/out.
//
// R6: two-phase, latency-oriented redesign.
// Profile R5: 48.5 us kernel, HBM 14%, Mfma 1.5%, VALU 8.5%, occ 16.8% ->
// pure latency-bound (serial 4-chunk barrier loop, 8 waves/CU, VGPR-throttled
// staging chains, w transposed 4x per q).
// K1: w fp32 -> wb bf16 in FRAGMENT-MAJOR layout: unit u = [q7][kt4][nt2][o_lo1][lane6]
//     holds the 8 bf16 (k=0..7) of B-fragment lane (quad=i&3, l16=c&15).
//     A wave's B-fragment load in K2 is ONE coalesced 1 KB dwordx4 burst.
// K2: grid 1024 = (q 128 x bq 8), b-tile 16, 4 waves = (o_lo, c-half).
//     A staged ONCE (full K) into 40 KB LDS (R5-verified ASTR=20 layout),
//     ONE barrier, then 16 MFMA-steps with B read direct from wb (L2-hot,
//     128 KB/q shared by 8 blocks on one XCD). launch_bounds(256,4):
//     16 waves/CU, no barriers in compute -> loads pipeline against MFMA.

#define CIN_  64
#define COUT_ 64
#define OD_   256
#define K_    8
#define L_    1028

#define ASTR 20   // A_lds row stride in bf16 elems (40 B: non-pow2 -> low conflict)

typedef __attribute__((ext_vector_type(8))) short bf16x8;
typedef __attribute__((ext_vector_type(4))) short short4v;
typedef __attribute__((ext_vector_type(4))) float floatx4;

__device__ __forceinline__ unsigned short f32_to_bf16(float f) {
    union { float f; uint32_t u; } v; v.f = f;
    uint32_t u = v.u;
    u += 0x7FFFu + ((u >> 16) & 1u);   // round-to-nearest-even
    return (unsigned short)(u >> 16);
}

// ---------------- K1: w fp32 -> wb bf16, fragment-major ----------------
// 1024 blocks x 256 threads x 4 units; unit = 8 contiguous bf16 (16 B).
__global__ __launch_bounds__(256, 8)
void lc1d_wprep(const float* __restrict__ w, unsigned short* __restrict__ wb) {
    const int tid = threadIdx.x;
    const int blk = blockIdx.x;
    #pragma unroll
    for (int it = 0; it < 4; ++it) {
        const int unit = blk * 1024 + it * 256 + tid;
        const int l16  = unit & 15;
        const int quad = (unit >> 4) & 3;
        const int o_lo = (unit >> 6) & 1;
        const int nt   = (unit >> 7) & 3;
        const int kt   = (unit >> 9) & 15;
        const int q    = unit >> 13;
        const int c    = nt * 16 + l16;
        const int i    = kt * 4 + quad;
        const int o    = q * 2 + o_lo;
        const float4* p = (const float4*)(w + ((size_t)((c * CIN_ + i) * OD_ + o) << 3));
        const float4 v0 = p[0];
        const float4 v1 = p[1];
        bf16x8 g;
        g[0] = f32_to_bf16(v0.x); g[1] = f32_to_bf16(v0.y);
        g[2] = f32_to_bf16(v0.z); g[3] = f32_to_bf16(v0.w);
        g[4] = f32_to_bf16(v1.x); g[5] = f32_to_bf16(v1.y);
        g[6] = f32_to_bf16(v1.z); g[7] = f32_to_bf16(v1.w);
        *(bf16x8*)&wb[(size_t)unit << 3] = g;
    }
}

// ---------------- K2: GEMM. block = (q, b-eighth), grid 1024 ----------------
__global__ __launch_bounds__(256, 4)
void lc1d_gemm(const float* __restrict__ x,
               const unsigned short* __restrict__ wb,
               float* __restrict__ out) {
    __shared__ __align__(16) unsigned short Al[64 * 16 * ASTR];  // 40 KB, full K

    const int tid = threadIdx.x;
    const int blk = blockIdx.x;
    // XCD swizzle: XCD k hosts q in [16k,16k+16) for all b-eighths
    const int q   = (blk & 7) * 16 + ((blk >> 3) & 15);
    const int bq  = blk >> 7;           // 0..7
    const int b0  = bq * 16;

    const int wave = tid >> 6;
    const int lane = tid & 63;
    const int quad = lane >> 4;
    const int l16  = lane & 15;
    const int o_lo = wave & 1;          // which o of the pair
    const int nth  = wave >> 1;         // c-half (nt = nth*2 + n)

    // ---- A staging: rows (iL 0..63, bL 0..15) x 12 floats [8q, 8q+12) ----
    #pragma unroll
    for (int it = 0; it < 16; ++it) {
        const int u   = it * 256 + tid;
        const int t   = u & 3;          // float4 within row; t==3 masked
        const int row = u >> 2;         // 0..1023
        const int bL  = row & 15;
        const int iL  = row >> 4;       // 0..63
        if (t < 3) {
            const float4 v = *(const float4*)(x +
                (size_t)((b0 + bL) * CIN_ + iL) * L_ + q * 8 + t * 4);
            ushort4 sv = make_ushort4(f32_to_bf16(v.x), f32_to_bf16(v.y),
                                      f32_to_bf16(v.z), f32_to_bf16(v.w));
            *(ushort4*)&Al[(iL * 16 + bL) * ASTR + t * 4] = sv;
        }
    }
    __syncthreads();   // single barrier of the kernel

    floatx4 acc[2];
    acc[0] = (floatx4){0.f, 0.f, 0.f, 0.f};
    acc[1] = (floatx4){0.f, 0.f, 0.f, 0.f};

    // ---- compute: 16 K-steps of 32 (i = kt*4+quad, k = 0..7) ----
    #pragma unroll
    for (int kt = 0; kt < 16; ++kt) {
        const int abase = ((kt * 4 + quad) * 16 + l16) * ASTR + o_lo * 4;
        const short4v a_lo = *(const short4v*)&Al[abase];
        const short4v a_hi = *(const short4v*)&Al[abase + 4];
        bf16x8 af;
        af[0] = a_lo[0]; af[1] = a_lo[1]; af[2] = a_lo[2]; af[3] = a_lo[3];
        af[4] = a_hi[0]; af[5] = a_hi[1]; af[6] = a_hi[2]; af[7] = a_hi[3];
        #pragma unroll
        for (int n = 0; n < 2; ++n) {
            const int nt = nth * 2 + n;
            // wb unit = [q][kt][nt][o_lo][lane], 8 bf16 each -> 1 KB/wave coalesced
            const bf16x8 bf = *(const bf16x8*)&wb[
                ((size_t)(((q * 16 + kt) * 4 + nt) * 2 + o_lo) << 9) + (lane << 3)];
            acc[n] = __builtin_amdgcn_mfma_f32_16x16x32_bf16(af, bf, acc[n], 0, 0, 0);
        }
    }

    // ---- epilogue: D col=l16 (c), row=quad*4+reg (b); scale 1/sqrt(64) ----
    const int o_g = q * 2 + o_lo;
    #pragma unroll
    for (int n = 0; n < 2; ++n) {
        const int c = (nth * 2 + n) * 16 + l16;
        #pragma unroll
        for (int r = 0; r < 4; ++r) {
            const int b = b0 + quad * 4 + r;
            out[((size_t)b * COUT_ + c) * OD_ + o_g] = acc[n][r] * 0.125f;
        }
    }
}

extern "C" void kernel_launch(void* const* d_in, const int* in_sizes, int n_in,
                              void* d_out, int out_size, void* d_ws, size_t ws_size,
                              hipStream_t stream) {
    const float* x = (const float*)d_in[0];   // (128, 64, 1028)
    const float* w = (const float*)d_in[1];   // (1, 64, 64, 256, 8)
    float* out = (float*)d_out;               // (128, 64, 256)
    unsigned short* wb = (unsigned short*)d_ws; // 16.8 MB bf16 fragment-major

    hipLaunchKernelGGL(lc1d_wprep, dim3(1024), dim3(256), 0, stream, w, wb);
    hipLaunchKernelGGL(lc1d_gemm,  dim3(1024), dim3(256), 0, stream, x, wb, out);
}